// Round 8
// baseline (966.425 us; speedup 1.0000x reference)
//
#include <hip/hip_runtime.h>
#include <hip/hip_bf16.h>
#include <math.h>

// Problem constants
#define BB 256
#define T2C 1026
#define TP1 1025
#define SS 1024
#define HH 32
#define EVN 32
#define VOCAB 35
#define NH7 224            // 7*H
#define NROWS 262400       // B*Tp1
#define EPSF 2.220446049250313e-16f

// ws layout in floats:
//  [0, NROWS*128)          ccdo rows: per (b,t): interleaved j*4 + {c,cbar,delta,o}
//  [EMBW_F, +35*224)       EmbW (x@W[:32,:] + b per vocab word)
//  [ACC_F, +4096)          per-(b,quarter): numer[1024] | den[1024] | loglam[1024] | nev[1024]
#define EMBW_F ((size_t)NROWS * 128)               // 33,587,200
#define ACC_F  (EMBW_F + (size_t)VOCAB * NH7)
#define NUM0   (ACC_F)
#define DEN0   (ACC_F + 1024)
#define LL0    (ACC_F + 2048)
#define NEV0   (ACC_F + 3072)

__device__ __forceinline__ float rcp_(float x) { return __builtin_amdgcn_rcpf(x); }
__device__ __forceinline__ float sig_(float x) { return rcp_(1.f + __expf(-x)); }
__device__ __forceinline__ float tanh_(float x) { return fmaf(2.f, rcp_(1.f + __expf(-2.f * x)), -1.f); }
__device__ __forceinline__ float softplus_(float x) {
    return fmaxf(x, 0.f) + __logf(1.f + __expf(-fabsf(x)));
}
// lo lanes (l<32) receive x from lane l+32
__device__ __forceinline__ float swap_hi_to_lo(float x) {
    float a = x, b = x;
    asm volatile("v_permlane32_swap_b32 %0, %1" : "+v"(a), "+v"(b));
    return a;
}

// ---------------- K0: EmbW precompute ----------------
__global__ __launch_bounds__(256) void k0_embw(const float* __restrict__ Emb,
                                               const float* __restrict__ W,
                                               const float* __restrict__ bias,
                                               float* __restrict__ ws) {
    int j = threadIdx.x;
    __shared__ float embs[VOCAB * HH];
    for (int idx = j; idx < VOCAB * HH; idx += 256) embs[idx] = Emb[idx];
    __syncthreads();
    if (j < NH7) {
        for (int v = 0; v < VOCAB; v++) {
            float s = bias[j];
#pragma unroll
            for (int k = 0; k < HH; k++) s = fmaf(embs[v * HH + k], W[k * NH7 + j], s);
            ws[EMBW_F + v * NH7 + j] = s;
        }
    }
}

// ---------------- K1: sequential CTLSTM scan — ONE WAVE per batch ----------------
// W streamed from LDS (w4[k][lane] float4, ds_read_b128 with imm offsets): the
// VGPR working set drops to ~65 regs, eliminating the 132-VGPR allocator wall
// that kept R4-R7 at ~950 VALU-issue cyc/step. h broadcast via LDS b128 reads
// (DS pipe) instead of 32 v_readlane (VALU pipe). Single wave: DS in-order,
// no barriers in the loop.
// Lane l owns columns {l, l+64, l+128, l+192(lo only)}:
//   l<32 : gates i(c0), z(c1), ib(c2), d(c3) of hidden j=l
//   l>=32: gates f(c0), o(c1), fb(c2)        of hidden j=l-32
__global__ __launch_bounds__(64) void k1_recur(const int* __restrict__ event,
                                               const float* __restrict__ dtime,
                                               const float* __restrict__ W,
                                               float* __restrict__ ws) {
    const int b = blockIdx.x;
    const int l = threadIdx.x;  // 0..63
    __shared__ __align__(16) float4 w4[HH][64];       // 32 KB  W2 cols per lane
    __shared__ __align__(16) float4 embp[VOCAB][64];  // 35 KB  packed EmbW per lane
    __shared__ float dt_s[TP1 + 1];
    __shared__ int ev_s[TP1 + 1];
    __shared__ __align__(16) float h_s[HH];

    const bool lo = (l < HH);
    const int c0 = l, c1 = l + 64, c2 = l + 128, c3 = l + 192;

    // stage W2 columns: w4[k][l] = (W2[k][c0], W2[k][c1], W2[k][c2], lo?W2[k][c3]:0)
    for (int k = 0; k < HH; k++) {
        const float* wr = W + (HH + k) * NH7;
        w4[k][l] = make_float4(wr[c0], wr[c1], wr[c2], lo ? wr[c3] : 0.f);
    }
    // packed per-lane EmbW table: one ds_read_b128 per step
    for (int v = 0; v < VOCAB; v++) {
        const float* e = ws + EMBW_F + v * NH7;
        embp[v][l] = make_float4(e[c0], e[c1], e[c2], lo ? e[c3] : 0.f);
    }
    for (int idx = l; idx < TP1; idx += 64) {
        ev_s[idx] = event[b * T2C + idx];
        dt_s[idx] = dtime[b * T2C + idx + 1];
    }
    if (l == 0) { ev_s[TP1] = 0; dt_s[TP1] = 0.f; }
    if (lo) h_s[l] = 0.f;

    float* ccdo_base = ws + (size_t)b * TP1 * 128;
    __syncthreads();

    float c_m = 0.f, cb_m = 0.f;
    float4 eb = embp[ev_s[0]][l];
    float dtc = dt_s[0];
    const float4* h4 = (const float4*)h_s;

    for (int t = 0; t < TP1; t++) {
        float a0 = eb.x, a1 = eb.y, a2 = eb.z, a3 = eb.w;
        const float dt = dtc;
        // h broadcast: 8 uniform-address ds_read_b128 (reads previous step's write;
        // same-wave DS ordering, no barrier)
        float4 hv0 = h4[0], hv1 = h4[1], hv2 = h4[2], hv3 = h4[3];
        float4 hv4 = h4[4], hv5 = h4[5], hv6 = h4[6], hv7 = h4[7];
        // prefetch next step's eb/dt
        eb = embp[ev_s[t + 1]][l];
        dtc = dt_s[t + 1];
        // GEMV: 32 x ds_read_b128 (imm offsets) feeding 128 FMAs
        const float h_all[HH] = {hv0.x, hv0.y, hv0.z, hv0.w, hv1.x, hv1.y, hv1.z, hv1.w,
                                 hv2.x, hv2.y, hv2.z, hv2.w, hv3.x, hv3.y, hv3.z, hv3.w,
                                 hv4.x, hv4.y, hv4.z, hv4.w, hv5.x, hv5.y, hv5.z, hv5.w,
                                 hv6.x, hv6.y, hv6.z, hv6.w, hv7.x, hv7.y, hv7.z, hv7.w};
#pragma unroll
        for (int k = 0; k < HH; k++) {
            float4 w = w4[k][l];
            float hk = h_all[k];
            a0 = fmaf(hk, w.x, a0);
            a1 = fmaf(hk, w.y, a1);
            a2 = fmaf(hk, w.z, a2);
            a3 = fmaf(hk, w.w, a3);
        }
        // activations
        float g0 = sig_(a0);                       // i | f
        float g2 = sig_(a2);                       // ib | fb
        float y1 = lo ? a1 + a1 : a1;
        float s1 = sig_(y1);
        float g1 = lo ? fmaf(2.f, s1, -1.f) : s1;  // tanh(z) | sigmoid(o)
        float g3 = softplus_(a3);                  // delta (valid on lo)
        float e  = __expf(-g3 * dt);
        // hi -> lo half swap (VALU permlane, no LDS)
        float f_  = swap_hi_to_lo(g0);
        float o_  = swap_hi_to_lo(g1);
        float fb_ = swap_hi_to_lo(g2);
        // update (all lanes execute; hi lanes produce garbage, never read)
        float cc = fmaf(f_, c_m, g0 * g1);
        float cb = fmaf(fb_, cb_m, g2 * g1);
        float cn = fmaf(cc - cb, e, cb);
        float hn = o_ * tanh_(cn);
        c_m = cn; cb_m = cb;
        if (lo) {
            h_s[l] = hn;
            ((float4*)(ccdo_base + (size_t)t * 128))[l] = make_float4(cc, cb, g3, o_);
        }
    }
}

// ---------------- K2: lambda_sample + per-batch integral (grid 256x4, no atomics) ----------------
__global__ __launch_bounds__(256) void k2_sample(const float* __restrict__ dts,
                                                 const float* __restrict__ msk,
                                                 const float* __restrict__ Wl,
                                                 float* ws,
                                                 float* __restrict__ out) {
    __shared__ __align__(16) float sh_s[8][HH];
    __shared__ float redn[8], redd[8];
    const int tid = threadIdx.x;
    const int b = blockIdx.x, q4 = blockIdx.y;
    const int rowg = tid >> 5, lane = tid & 31;
    float4 wl4[8];
#pragma unroll
    for (int q = 0; q < 8; q++) wl4[q] = ((const float4*)(Wl + lane * HH))[q];

    const int base = b * SS + q4 * 256;
    float accn = 0.f, accd = 0.f;

#pragma unroll 2
    for (int it = 0; it < 32; it++) {
        const size_t rr = (size_t)base + it * 8 + rowg;
        float4 v = *(const float4*)(ws + rr * 128 + lane * 4);  // c, cbar, delta, o
        float e_ = __expf(-v.z * dts[rr]);
        float cd = fmaf(v.x - v.y, e_, v.y);
        sh_s[rowg][lane] = v.w * tanh_(cd);   // same-wave write/read, no barrier
        const float4* sh4 = (const float4*)sh_s[rowg];
        float acc = 0.f, acc2 = 0.f;
#pragma unroll
        for (int q = 0; q < 4; q++) {
            float4 s4 = sh4[q];
            acc  = fmaf(s4.x, wl4[q].x, acc);  acc  = fmaf(s4.y, wl4[q].y, acc);
            acc  = fmaf(s4.z, wl4[q].z, acc);  acc  = fmaf(s4.w, wl4[q].w, acc);
        }
#pragma unroll
        for (int q = 4; q < 8; q++) {
            float4 s4 = sh4[q];
            acc2 = fmaf(s4.x, wl4[q].x, acc2); acc2 = fmaf(s4.y, wl4[q].y, acc2);
            acc2 = fmaf(s4.z, wl4[q].z, acc2); acc2 = fmaf(s4.w, wl4[q].w, acc2);
        }
        float sp = softplus_(acc + acc2);
        out[2 + rr * EVN + lane] = sp;
        float ls = sp;
#pragma unroll
        for (int m = 16; m >= 1; m >>= 1) ls += __shfl_xor(ls, m);
        float m_ = msk[rr];
        accn = fmaf(ls, m_, accn);
        accd += m_;
    }
    if (lane == 0) { redn[rowg] = accn; redd[rowg] = accd; }
    __syncthreads();
    if (tid == 0) {
        float n = 0.f, d = 0.f;
#pragma unroll
        for (int g = 0; g < 8; g++) { n += redn[g]; d += redd[g]; }
        ws[NUM0 + q4 * 256 + b] = n;
        ws[DEN0 + q4 * 256 + b] = d;
    }
}

// ---------------- K3: log-lambda at target (recomputes h from ccdo) ----------------
__global__ __launch_bounds__(256) void k3_loglam(const int* __restrict__ event,
                                                 const float* __restrict__ dtime,
                                                 const float* __restrict__ Wl,
                                                 float* ws) {
    __shared__ float wl_s[EVN * HH];
    __shared__ float redl[8], redc[8];
    const int tid = threadIdx.x;
    const int b = blockIdx.x, q4 = blockIdx.y;
    for (int idx = tid; idx < EVN * HH; idx += 256) wl_s[idx] = Wl[idx];
    const int rowg = tid >> 5, lane = tid & 31;
    const int t_end = (q4 < 3) ? (q4 + 1) * 256 : TP1;
    float accl = 0.f, accc = 0.f;
    __syncthreads();

    for (int t = q4 * 256 + rowg; t < t_end; t += 8) {
        int tgt = event[b * T2C + t + 1];
        if (tgt < EVN) {
            float4 v = *(const float4*)(ws + ((size_t)b * TP1 + t) * 128 + lane * 4);
            float dt = dtime[b * T2C + t + 1];
            float e_ = __expf(-v.z * dt);
            float cd = fmaf(v.x - v.y, e_, v.y);
            float h = v.w * tanh_(cd);
            float p = h * wl_s[tgt * HH + lane];
#pragma unroll
            for (int m = 16; m >= 1; m >>= 1) p += __shfl_xor(p, m);
            accl += __logf(softplus_(p) + EPSF);
            accc += 1.f;
        }
    }
    if (lane == 0) { redl[rowg] = accl; redc[rowg] = accc; }
    __syncthreads();
    if (tid == 0) {
        float l = 0.f, c = 0.f;
#pragma unroll
        for (int g = 0; g < 8; g++) { l += redl[g]; c += redc[g]; }
        ws[LL0 + q4 * 256 + b] = l;
        ws[NEV0 + q4 * 256 + b] = c;
    }
}

// ---------------- K4: final reduction ----------------
__global__ __launch_bounds__(256) void k4_final(const float* __restrict__ duration,
                                                float* ws,
                                                float* __restrict__ out) {
    __shared__ float r1[256], r2[256];
    int tid = threadIdx.x;
    float nmr = 0.f, den = 0.f, llb = 0.f, nev = 0.f;
#pragma unroll
    for (int q = 0; q < 4; q++) {
        nmr += ws[NUM0 + q * 256 + tid];
        den += ws[DEN0 + q * 256 + tid];
        llb += ws[LL0 + q * 256 + tid];
        nev += ws[NEV0 + q * 256 + tid];
    }
    r1[tid] = (nmr / den) * duration[tid] - llb;
    r2[tid] = nev;
    __syncthreads();
    for (int ofs = 128; ofs > 0; ofs >>= 1) {
        if (tid < ofs) { r1[tid] += r1[tid + ofs]; r2[tid] += r2[tid + ofs]; }
        __syncthreads();
    }
    if (tid == 0) { out[0] = r1[0]; out[1] = r2[0]; }
}

extern "C" void kernel_launch(void* const* d_in, const int* in_sizes, int n_in,
                              void* d_out, int out_size, void* d_ws, size_t ws_size,
                              hipStream_t stream) {
    const int*   event    = (const int*)d_in[0];
    const float* dtime    = (const float*)d_in[1];
    const float* duration = (const float*)d_in[2];
    const float* dts      = (const float*)d_in[3];
    // d_in[4] index_of_hidden_sampling: dead in reference
    const float* msk      = (const float*)d_in[5];
    const float* Emb      = (const float*)d_in[6];
    const float* W        = (const float*)d_in[7];
    const float* bias     = (const float*)d_in[8];
    const float* Wl       = (const float*)d_in[9];
    float* out = (float*)d_out;
    float* ws  = (float*)d_ws;

    k0_embw<<<1, 256, 0, stream>>>(Emb, W, bias, ws);
    k1_recur<<<BB, 64, 0, stream>>>(event, dtime, W, ws);
    k2_sample<<<dim3(BB, 4), 256, 0, stream>>>(dts, msk, Wl, ws, out);
    k3_loglam<<<dim3(BB, 4), 256, 0, stream>>>(event, dtime, Wl, ws);
    k4_final<<<1, 256, 0, stream>>>(duration, ws, out);
}

// Round 10
// 508.710 us; speedup vs baseline: 1.8998x; 1.8998x over previous
//
#include <hip/hip_runtime.h>
#include <hip/hip_bf16.h>
#include <math.h>

// Problem constants
#define BB 256
#define T2C 1026
#define TP1 1025
#define SS 1024
#define HH 32
#define EVN 32
#define VOCAB 35
#define NH7 224            // 7*H
#define NROWS 262400       // B*Tp1
#define EPSF 2.220446049250313e-16f

// ws layout in floats:
//  [0, NROWS*128)          ccdo rows: per (b,t): interleaved j*4 + {c,cbar,delta,o}
//  [EMBW_F, +35*224)       EmbW (x@W[:32,:] + b per vocab word), f32
//  [ACC_F, +4096)          per-(b,quarter): numer[1024] | den[1024] | loglam[1024] | nev[1024]
//  [W2P_F, +224*16)        W2 packed f16x2: uint at [col*16+kp] = (f16(W2[2kp][col]), f16(W2[2kp+1][col]))
#define EMBW_F ((size_t)NROWS * 128)               // 33,587,200
#define ACC_F  (EMBW_F + (size_t)VOCAB * NH7)
#define NUM0   (ACC_F)
#define DEN0   (ACC_F + 1024)
#define LL0    (ACC_F + 2048)
#define NEV0   (ACC_F + 3072)
#define W2P_F  (ACC_F + 4096)

typedef __fp16 h2t __attribute__((ext_vector_type(2)));
union PkU { unsigned int u; h2t h; };

__device__ __forceinline__ float rcp_(float x) { return __builtin_amdgcn_rcpf(x); }
__device__ __forceinline__ float sig_(float x) { return rcp_(1.f + __expf(-x)); }
__device__ __forceinline__ float tanh_(float x) { return fmaf(2.f, rcp_(1.f + __expf(-2.f * x)), -1.f); }
__device__ __forceinline__ float softplus_(float x) {
    return fmaxf(x, 0.f) + __logf(1.f + __expf(-fabsf(x)));
}
// lo lanes (l<32) receive x from lane l+32
__device__ __forceinline__ float swap_hi_to_lo(float x) {
    float a = x, b = x;
    asm volatile("v_permlane32_swap_b32 %0, %1" : "+v"(a), "+v"(b));
    return a;
}

// ---------------- K0: EmbW precompute + W2 f16 packing ----------------
__global__ __launch_bounds__(256) void k0_embw(const float* __restrict__ Emb,
                                               const float* __restrict__ W,
                                               const float* __restrict__ bias,
                                               float* __restrict__ ws) {
    int j = threadIdx.x;
    __shared__ float embs[VOCAB * HH];
    for (int idx = j; idx < VOCAB * HH; idx += 256) embs[idx] = Emb[idx];
    // W2 packed f16 pairs: u[col*16+kp] = pack(W2[2kp][col], W2[2kp+1][col])
    unsigned int* wp = (unsigned int*)(ws + W2P_F);
    for (int idx = j; idx < NH7 * 16; idx += 256) {
        int col = idx >> 4, kp = idx & 15;
        float w0 = W[(HH + 2 * kp) * NH7 + col];
        float w1 = W[(HH + 2 * kp + 1) * NH7 + col];
        PkU p; p.h = __builtin_amdgcn_cvt_pkrtz(w0, w1);
        wp[idx] = p.u;
    }
    __syncthreads();
    if (j < NH7) {
        for (int v = 0; v < VOCAB; v++) {
            float s = bias[j];
#pragma unroll
            for (int k = 0; k < HH; k++) s = fmaf(embs[v * HH + k], W[k * NH7 + j], s);
            ws[EMBW_F + v * NH7 + j] = s;
        }
    }
}

// ---------------- K1: sequential CTLSTM scan — ONE WAVE per batch ----------------
// GEMV via v_dot2_f32_f16: weights live as 64 packed-f16x2 VGPRs (under the
// 132-VGPR allocator wall that caused AGPR copy traffic in R4-R7), h broadcast
// as 16 packed SGPRs via cvt_pkrtz + DPP + readlane. ~64 dot2 + ~70 misc VALU
// per step. No LDS writes in the loop; eb/dt prefetched one step ahead.
// Lane l owns columns {l, l+64, l+128, l+192(lo only)}:
//   l<32 : gates i(c0), z(c1), ib(c2), d(c3) of hidden j=l
//   l>=32: gates f(c0), o(c1), fb(c2)        of hidden j=l-32
__global__ __launch_bounds__(64) void k1_recur(const int* __restrict__ event,
                                               const float* __restrict__ dtime,
                                               float* __restrict__ ws) {
    const int b = blockIdx.x;
    const int l = threadIdx.x;  // 0..63
    __shared__ __align__(16) float4 embp[VOCAB][64];  // 35 KB packed EmbW per lane
    __shared__ float dt_s[TP1 + 1];
    __shared__ int ev_s[TP1 + 1];

    const bool lo = (l < HH);
    const int c0 = l, c1 = l + 64, c2 = l + 128, c3 = lo ? (l + 192) : l;

    // packed per-lane EmbW (f32 accumulator seeds): one ds_read_b128 per step
    for (int v = 0; v < VOCAB; v++) {
        const float* e = ws + EMBW_F + v * NH7;
        embp[v][l] = make_float4(e[c0], e[c1], e[c2], lo ? e[c3] : 0.f);
    }
    for (int idx = l; idx < TP1; idx += 64) {
        ev_s[idx] = event[b * T2C + idx];
        dt_s[idx] = dtime[b * T2C + idx + 1];
    }
    if (l == 0) { ev_s[TP1] = 0; dt_s[TP1] = 0.f; }

    // per-lane packed f16 weight columns: wk[g][kp] = (W2[2kp][cg], W2[2kp+1][cg])
    h2t wk0[16], wk1[16], wk2[16], wk3[16];
    {
        const uint4* wp = (const uint4*)(ws + W2P_F);
#pragma unroll
        for (int q = 0; q < 4; q++) {
            uint4 u0 = wp[c0 * 4 + q], u1 = wp[c1 * 4 + q], u2 = wp[c2 * 4 + q];
            uint4 u3 = lo ? wp[c3 * 4 + q] : make_uint4(0, 0, 0, 0);
            PkU p;
            p.u = u0.x; wk0[4 * q] = p.h;     p.u = u0.y; wk0[4 * q + 1] = p.h;
            p.u = u0.z; wk0[4 * q + 2] = p.h; p.u = u0.w; wk0[4 * q + 3] = p.h;
            p.u = u1.x; wk1[4 * q] = p.h;     p.u = u1.y; wk1[4 * q + 1] = p.h;
            p.u = u1.z; wk1[4 * q + 2] = p.h; p.u = u1.w; wk1[4 * q + 3] = p.h;
            p.u = u2.x; wk2[4 * q] = p.h;     p.u = u2.y; wk2[4 * q + 1] = p.h;
            p.u = u2.z; wk2[4 * q + 2] = p.h; p.u = u2.w; wk2[4 * q + 3] = p.h;
            p.u = u3.x; wk3[4 * q] = p.h;     p.u = u3.y; wk3[4 * q + 1] = p.h;
            p.u = u3.z; wk3[4 * q + 2] = p.h; p.u = u3.w; wk3[4 * q + 3] = p.h;
        }
    }
    float* ccdo_base = ws + (size_t)b * TP1 * 128;
    __syncthreads();

    float hprev = 0.f, c_m = 0.f, cb_m = 0.f;
    float4 eb = embp[ev_s[0]][l];
    float dtc = dt_s[0];

    for (int t = 0; t < TP1; t++) {
        float a0 = eb.x, a1 = eb.y, a2 = eb.z, a3 = eb.w;
        const float dt = dtc;
        // prefetch next step's eb/dt (independent, hides LDS latency)
        eb = embp[ev_s[t + 1]][l];
        dtc = dt_s[t + 1];
        // pack h pairs: even lane 2k holds (h[2k], h[2k+1]); broadcast via readlane
        float hsw = __uint_as_float(__builtin_amdgcn_mov_dpp(
            __float_as_uint(hprev), 0xB1, 0xF, 0xF, true));  // quad_perm [1,0,3,2]
        PkU pk; pk.h = __builtin_amdgcn_cvt_pkrtz(hprev, hsw);
        unsigned int sh[16];
#pragma unroll
        for (int k = 0; k < 16; k++) sh[k] = (unsigned int)__builtin_amdgcn_readlane((int)pk.u, 2 * k);
        // GEMV: 64 x v_dot2_f32_f16, 4 independent 16-deep chains
#pragma unroll
        for (int k = 0; k < 16; k++) {
            PkU hp; hp.u = sh[k];
            a0 = __builtin_amdgcn_fdot2(wk0[k], hp.h, a0, false);
            a1 = __builtin_amdgcn_fdot2(wk1[k], hp.h, a1, false);
            a2 = __builtin_amdgcn_fdot2(wk2[k], hp.h, a2, false);
            a3 = __builtin_amdgcn_fdot2(wk3[k], hp.h, a3, false);
        }
        // activations
        float g0 = sig_(a0);                       // i | f
        float g2 = sig_(a2);                       // ib | fb
        float y1 = lo ? a1 + a1 : a1;
        float s1 = sig_(y1);
        float g1 = lo ? fmaf(2.f, s1, -1.f) : s1;  // tanh(z) | sigmoid(o)
        float g3 = softplus_(a3);                  // delta (valid on lo)
        float e  = __expf(-g3 * dt);
        // hi -> lo half swap (VALU permlane, no LDS)
        float f_  = swap_hi_to_lo(g0);
        float o_  = swap_hi_to_lo(g1);
        float fb_ = swap_hi_to_lo(g2);
        // update (all lanes execute; hi-lane values are garbage, never read)
        float cc = fmaf(f_, c_m, g0 * g1);
        float cb = fmaf(fb_, cb_m, g2 * g1);
        float cn = fmaf(cc - cb, e, cb);
        float hn = o_ * tanh_(cn);
        c_m = cn; cb_m = cb;
        if (lo)
            ((float4*)(ccdo_base + (size_t)t * 128))[l] = make_float4(cc, cb, g3, o_);
        hprev = hn;
    }
}

// ---------------- K2: lambda_sample + per-batch integral (grid 256x4, no atomics) ----------------
__global__ __launch_bounds__(256) void k2_sample(const float* __restrict__ dts,
                                                 const float* __restrict__ msk,
                                                 const float* __restrict__ Wl,
                                                 float* ws,
                                                 float* __restrict__ out) {
    __shared__ __align__(16) float sh_s[8][HH];
    __shared__ float redn[8], redd[8];
    const int tid = threadIdx.x;
    const int b = blockIdx.x, q4 = blockIdx.y;
    const int rowg = tid >> 5, lane = tid & 31;
    float4 wl4[8];
#pragma unroll
    for (int q = 0; q < 8; q++) wl4[q] = ((const float4*)(Wl + lane * HH))[q];

    const int base = b * SS + q4 * 256;
    float accn = 0.f, accd = 0.f;

#pragma unroll 2
    for (int it = 0; it < 32; it++) {
        const size_t rr = (size_t)base + it * 8 + rowg;
        float4 v = *(const float4*)(ws + rr * 128 + lane * 4);  // c, cbar, delta, o
        float e_ = __expf(-v.z * dts[rr]);
        float cd = fmaf(v.x - v.y, e_, v.y);
        sh_s[rowg][lane] = v.w * tanh_(cd);   // same-wave write/read, no barrier
        const float4* sh4 = (const float4*)sh_s[rowg];
        float acc = 0.f, acc2 = 0.f;
#pragma unroll
        for (int q = 0; q < 4; q++) {
            float4 s4 = sh4[q];
            acc  = fmaf(s4.x, wl4[q].x, acc);  acc  = fmaf(s4.y, wl4[q].y, acc);
            acc  = fmaf(s4.z, wl4[q].z, acc);  acc  = fmaf(s4.w, wl4[q].w, acc);
        }
#pragma unroll
        for (int q = 4; q < 8; q++) {
            float4 s4 = sh4[q];
            acc2 = fmaf(s4.x, wl4[q].x, acc2); acc2 = fmaf(s4.y, wl4[q].y, acc2);
            acc2 = fmaf(s4.z, wl4[q].z, acc2); acc2 = fmaf(s4.w, wl4[q].w, acc2);
        }
        float sp = softplus_(acc + acc2);
        out[2 + rr * EVN + lane] = sp;
        float ls = sp;
#pragma unroll
        for (int m = 16; m >= 1; m >>= 1) ls += __shfl_xor(ls, m);
        float m_ = msk[rr];
        accn = fmaf(ls, m_, accn);
        accd += m_;
    }
    if (lane == 0) { redn[rowg] = accn; redd[rowg] = accd; }
    __syncthreads();
    if (tid == 0) {
        float n = 0.f, d = 0.f;
#pragma unroll
        for (int g = 0; g < 8; g++) { n += redn[g]; d += redd[g]; }
        ws[NUM0 + q4 * 256 + b] = n;
        ws[DEN0 + q4 * 256 + b] = d;
    }
}

// ---------------- K3: log-lambda at target (recomputes h from ccdo) ----------------
__global__ __launch_bounds__(256) void k3_loglam(const int* __restrict__ event,
                                                 const float* __restrict__ dtime,
                                                 const float* __restrict__ Wl,
                                                 float* ws) {
    __shared__ float wl_s[EVN * HH];
    __shared__ float redl[8], redc[8];
    const int tid = threadIdx.x;
    const int b = blockIdx.x, q4 = blockIdx.y;
    for (int idx = tid; idx < EVN * HH; idx += 256) wl_s[idx] = Wl[idx];
    const int rowg = tid >> 5, lane = tid & 31;
    const int t_end = (q4 < 3) ? (q4 + 1) * 256 : TP1;
    float accl = 0.f, accc = 0.f;
    __syncthreads();

    for (int t = q4 * 256 + rowg; t < t_end; t += 8) {
        int tgt = event[b * T2C + t + 1];
        if (tgt < EVN) {
            float4 v = *(const float4*)(ws + ((size_t)b * TP1 + t) * 128 + lane * 4);
            float dt = dtime[b * T2C + t + 1];
            float e_ = __expf(-v.z * dt);
            float cd = fmaf(v.x - v.y, e_, v.y);
            float h = v.w * tanh_(cd);
            float p = h * wl_s[tgt * HH + lane];
#pragma unroll
            for (int m = 16; m >= 1; m >>= 1) p += __shfl_xor(p, m);
            accl += __logf(softplus_(p) + EPSF);
            accc += 1.f;
        }
    }
    if (lane == 0) { redl[rowg] = accl; redc[rowg] = accc; }
    __syncthreads();
    if (tid == 0) {
        float l = 0.f, c = 0.f;
#pragma unroll
        for (int g = 0; g < 8; g++) { l += redl[g]; c += redc[g]; }
        ws[LL0 + q4 * 256 + b] = l;
        ws[NEV0 + q4 * 256 + b] = c;
    }
}

// ---------------- K4: final reduction ----------------
__global__ __launch_bounds__(256) void k4_final(const float* __restrict__ duration,
                                                float* ws,
                                                float* __restrict__ out) {
    __shared__ float r1[256], r2[256];
    int tid = threadIdx.x;
    float nmr = 0.f, den = 0.f, llb = 0.f, nev = 0.f;
#pragma unroll
    for (int q = 0; q < 4; q++) {
        nmr += ws[NUM0 + q * 256 + tid];
        den += ws[DEN0 + q * 256 + tid];
        llb += ws[LL0 + q * 256 + tid];
        nev += ws[NEV0 + q * 256 + tid];
    }
    r1[tid] = (nmr / den) * duration[tid] - llb;
    r2[tid] = nev;
    __syncthreads();
    for (int ofs = 128; ofs > 0; ofs >>= 1) {
        if (tid < ofs) { r1[tid] += r1[tid + ofs]; r2[tid] += r2[tid + ofs]; }
        __syncthreads();
    }
    if (tid == 0) { out[0] = r1[0]; out[1] = r2[0]; }
}

extern "C" void kernel_launch(void* const* d_in, const int* in_sizes, int n_in,
                              void* d_out, int out_size, void* d_ws, size_t ws_size,
                              hipStream_t stream) {
    const int*   event    = (const int*)d_in[0];
    const float* dtime    = (const float*)d_in[1];
    const float* duration = (const float*)d_in[2];
    const float* dts      = (const float*)d_in[3];
    // d_in[4] index_of_hidden_sampling: dead in reference
    const float* msk      = (const float*)d_in[5];
    const float* Emb      = (const float*)d_in[6];
    const float* W        = (const float*)d_in[7];
    const float* bias     = (const float*)d_in[8];
    const float* Wl       = (const float*)d_in[9];
    float* out = (float*)d_out;
    float* ws  = (float*)d_ws;

    k0_embw<<<1, 256, 0, stream>>>(Emb, W, bias, ws);
    k1_recur<<<BB, 64, 0, stream>>>(event, dtime, ws);
    k2_sample<<<dim3(BB, 4), 256, 0, stream>>>(dts, msk, Wl, ws, out);
    k3_loglam<<<dim3(BB, 4), 256, 0, stream>>>(event, dtime, Wl, ws);
    k4_final<<<1, 256, 0, stream>>>(duration, ws, out);
}